// Round 2
// baseline (189.855 us; speedup 1.0000x reference)
//
#include <hip/hip_runtime.h>

// DropGCN: out = relu( mean_r( diag(k_r) A diag(k_r) X ) @ W^T + b )
//  == Y[8192,160] = A @ Xm   (Xm[:, r*32+d] = k_r .* X[:,d], bf16)
//  then per-row masked mean over the 5 replica slices, @W^T, +b, relu.
//
// Round 2: correctness-first rewrite. Plain reg-staged LDS (no
// global_load_lds), no swizzle, single-buffered slice, mask dtype
// auto-detected and normalized to u8 in ws.

#define N_NODES   8192
#define NSLICES   256          // 8192/32 K-slices
#define NCOLS     160          // 5 replicas * 32 dims
#define SLICE_US  5120         // ushorts per K-slice image (160*32)
#define MASK_N    40960        // 5*8192 mask elements
#define MASK_WS   65536        // ws bytes reserved for normalized mask

typedef __attribute__((ext_vector_type(4))) float f32x4;
typedef __attribute__((ext_vector_type(8))) short bf16x8;

__device__ __forceinline__ unsigned short f2bf(float f) {
  // round-to-nearest-even f32 -> bf16 bits
  unsigned int u = __builtin_bit_cast(unsigned int, f);
  return (unsigned short)((u + 0x7FFFu + ((u >> 16) & 1u)) >> 16);
}

// ---------------------------------------------------------------------------
// mask_norm: the harness may push the bool keep_mask as u8, int32, or f32.
// Detect from the first 64 words (i32 bools -> words in {0,1}; f32 bools ->
// {0, 0x3F800000}; packed u8 bools -> other patterns) and normalize to u8.
// ---------------------------------------------------------------------------
__global__ __launch_bounds__(256) void mask_norm_kernel(
    const void* __restrict__ raw, unsigned char* __restrict__ mk) {
  __shared__ int mode32;
  if (threadIdx.x == 0) {
    const unsigned int* w = (const unsigned int*)raw;
    int ok = 1;
    for (int i = 0; i < 64; ++i) {
      unsigned int v = w[i];
      if (!(v <= 1u || v == 0x3F800000u)) { ok = 0; break; }
    }
    mode32 = ok;
  }
  __syncthreads();
  int idx = blockIdx.x * 256 + threadIdx.x;   // grid covers MASK_N exactly
  unsigned char r;
  if (mode32) r = (unsigned char)(((const unsigned int*)raw)[idx] != 0u);
  else        r = (unsigned char)(((const unsigned char*)raw)[idx] != 0);
  mk[idx] = r;
}

// ---------------------------------------------------------------------------
// prep: XmG[s][n][kk] = bf16( mk[r][j] ? X[j][d] : 0 ),  j = s*32+kk,
// n = r*32+d. Linear layout (no swizzle this round).
// ---------------------------------------------------------------------------
__global__ __launch_bounds__(256) void prep_kernel(
    const float* __restrict__ X, const unsigned char* __restrict__ mk,
    unsigned short* __restrict__ XmG) {
  int tid = blockIdx.x * 256 + threadIdx.x;   // 0 .. 160*8192-1
  int j = tid & (N_NODES - 1);                // node / k index
  int n = tid >> 13;                          // 0..159
  int r = n >> 5, d = n & 31;
  float v = mk[r * N_NODES + j] ? X[j * 32 + d] : 0.0f;
  int s = j >> 5, kk = j & 31;
  XmG[s * SLICE_US + n * 32 + kk] = f2bf(v);
}

// ---------------------------------------------------------------------------
// gemm: per block 64 rows (4 waves x 16), all 160 cols, K range 8192/KS.
// MFMA: A-op = Xm^T fragment (LDS), B-op = A-matrix row (8 contiguous f32
// per lane from global, cvt bf16 in-register).
// D lane map (m89-verified): D[row=(lane>>4)*4+reg][col=lane&15];
// here row -> Y-column n (A-op side), col -> Y-row m (B-op side).
// Partials -> ws as C^T [KS][160][8192] f32.
// ---------------------------------------------------------------------------
__global__ __launch_bounds__(256, 2) void gemm_kernel(
    const float* __restrict__ A, const unsigned short* __restrict__ XmG,
    float* __restrict__ part, int KS) {
  __shared__ __align__(16) unsigned short xm[SLICE_US];   // 10 KB

  const int tid  = threadIdx.x;
  const int lane = tid & 63;
  const int w    = tid >> 6;        // wave 0..3
  const int n0   = lane & 15;
  const int kg   = lane >> 4;       // k-group 0..3 (8 elems each)
  const int steps  = NSLICES / KS;
  const int s_base = blockIdx.y * steps;
  const int base_m = blockIdx.x * 64 + w * 16;

  const float* aptr =
      A + (size_t)(base_m + n0) * N_NODES + s_base * 32 + kg * 8;
  const unsigned short* frag0 = xm + n0 * 32 + kg * 8;

  f32x4 acc[10];
#pragma unroll
  for (int i = 0; i < 10; ++i) acc[i] = (f32x4){0.f, 0.f, 0.f, 0.f};

  // register prefetch of this wave's A chunk for step 0
  f32x4 pa = __builtin_nontemporal_load((const f32x4*)aptr);
  f32x4 pb = __builtin_nontemporal_load((const f32x4*)(aptr + 4));

  for (int step = 0; step < steps; ++step) {
    const unsigned short* src = XmG + (size_t)(s_base + step) * SLICE_US;
    __syncthreads();                         // prior step's LDS reads done
    for (int c = tid; c < 640; c += 256) {   // 640 x 16B = one slice
      *(bf16x8*)(xm + c * 8) = *(const bf16x8*)(src + c * 8);
    }
    __syncthreads();                         // slice visible to all waves

    // prefetch next step's A registers (streaming)
    const int nxt = (step + 1 < steps) ? (step + 1) : step;
    const float* ap = aptr + (size_t)nxt * 32;
    f32x4 na = __builtin_nontemporal_load((const f32x4*)ap);
    f32x4 nb = __builtin_nontemporal_load((const f32x4*)(ap + 4));

    // B fragment: 8 bf16 along k (same lane->k map as A fragment; any
    // consistent permutation cancels in the dot product)
    bf16x8 bfrag;
#pragma unroll
    for (int e = 0; e < 4; ++e) {
      bfrag[e]     = (short)f2bf(pa[e]);
      bfrag[4 + e] = (short)f2bf(pb[e]);
    }

#pragma unroll
    for (int nt = 0; nt < 10; ++nt) {
      bf16x8 af = *(const bf16x8*)(frag0 + nt * 512);
      acc[nt] = __builtin_amdgcn_mfma_f32_16x16x32_bf16(af, bfrag, acc[nt], 0, 0, 0);
    }
    pa = na; pb = nb;
  }

  // acc[nt][jj] = Y[base_m + n0][nt*16 + kg*4 + jj]; store C^T partials
  // part[s][n][m], coalesced in m across lanes 0..15.
  float* pout = part + (size_t)blockIdx.y * NCOLS * N_NODES + base_m + n0;
#pragma unroll
  for (int nt = 0; nt < 10; ++nt) {
#pragma unroll
    for (int jj = 0; jj < 4; ++jj) {
      int n = nt * 16 + kg * 4 + jj;
      pout[(size_t)n * N_NODES] = acc[nt][jj];
    }
  }
}

// ---------------------------------------------------------------------------
// epi: z[m,d] = 0.2 * sum_{s, r: mk[r][m]} part[s][r*32+d][m];
//      out[m,o] = relu(b[o] + sum_d z[d] * W[o,d])
// ---------------------------------------------------------------------------
__global__ __launch_bounds__(64) void epi_kernel(
    const float* __restrict__ part, const unsigned char* __restrict__ mk,
    const float* __restrict__ W, const float* __restrict__ bias,
    float* __restrict__ out, int KS) {
  int m = blockIdx.x * 64 + threadIdx.x;
  float z[32];
#pragma unroll
  for (int d = 0; d < 32; ++d) z[d] = 0.f;
  for (int s = 0; s < KS; ++s) {
    for (int r = 0; r < 5; ++r) {
      if (mk[r * N_NODES + m]) {
        const float* p = part + ((size_t)s * NCOLS + r * 32) * N_NODES + m;
#pragma unroll
        for (int d = 0; d < 32; ++d) z[d] += p[(size_t)d * N_NODES];
      }
    }
  }
#pragma unroll
  for (int d = 0; d < 32; ++d) z[d] *= 0.2f;
#pragma unroll
  for (int o = 0; o < 32; ++o) {
    float a = bias[o];
#pragma unroll
    for (int d = 0; d < 32; ++d) a = fmaf(z[d], W[o * 32 + d], a);
    out[(size_t)m * 32 + o] = fmaxf(a, 0.f);
  }
}

extern "C" void kernel_launch(void* const* d_in, const int* in_sizes, int n_in,
                              void* d_out, int out_size, void* d_ws, size_t ws_size,
                              hipStream_t stream) {
  const float* A = (const float*)d_in[0];
  const float* X = (const float*)d_in[1];
  const float* W = (const float*)d_in[2];
  const float* b = (const float*)d_in[3];
  const void*  keep_raw = (const void*)d_in[4];
  float* out = (float*)d_out;

  const size_t xm_bytes   = (size_t)NSLICES * SLICE_US * 2;   // 2,621,440
  const size_t part_bytes = (size_t)NCOLS * N_NODES * 4;      // 5,242,880
  const size_t base = MASK_WS + xm_bytes;

  int KS = 1;
  if (ws_size >= base + 4 * part_bytes) KS = 4;
  else if (ws_size >= base + 2 * part_bytes) KS = 2;
  if (ws_size < base + part_bytes) return;   // ws too small: fail loudly

  unsigned char* mk = (unsigned char*)d_ws;
  unsigned short* XmG = (unsigned short*)((char*)d_ws + MASK_WS);
  float* part = (float*)((char*)d_ws + base);

  mask_norm_kernel<<<dim3(MASK_N / 256), 256, 0, stream>>>(keep_raw, mk);
  prep_kernel<<<dim3((N_NODES * NCOLS) / 256), 256, 0, stream>>>(X, mk, XmG);
  gemm_kernel<<<dim3(N_NODES / 64, KS), 256, 0, stream>>>(A, XmG, part, KS);
  epi_kernel<<<dim3(N_NODES / 64), 64, 0, stream>>>(part, mk, W, b, out, KS);
}